// Round 11
// baseline (655.509 us; speedup 1.0000x reference)
//
#include <hip/hip_runtime.h>

typedef unsigned short u16;
typedef short bf16x8 __attribute__((ext_vector_type(8)));   // 8 bf16 (4 VGPRs)
typedef float f32x4 __attribute__((ext_vector_type(4)));
typedef unsigned long long u64;

__device__ __forceinline__ float bf2f(u16 u) {
  return __uint_as_float(((unsigned)u) << 16);
}
__device__ __forceinline__ u16 f2bf(float f) {
  unsigned u = __float_as_uint(f);
  u += 0x7fffu + ((u >> 16) & 1u);  // RNE (no NaNs in this workload)
  return (u16)(u >> 16);
}
__device__ __forceinline__ float rlf(float v, int l) {
  return __uint_as_float((unsigned)__builtin_amdgcn_readlane(__float_as_int(v), l));
}

// ---------------------------------------------------------------------------
// B=128, N=500. Stages A/B on 64000 unpermuted rows (permutation deferred to
// stage C). Stage C padded to 512 rows/batch -> 65536.
// ---------------------------------------------------------------------------
#define M_AB 64000
#define M_C 65536

#define OFF_ARENA_B 49152000u
#define OFF_IDX1 149815296u   // 128x500 int
#define OFF_FPSD 150071296u   // fps dist state
#define OFF_FPSI 150333440u   // fps fidx state
#define OFF_WB   150583296u   // bf16 weight arena (N,K padded)

// ---------------------------------------------------------------------------
// FPS: two independent batches per wave — the two dependency chains
// interleave and fill each other's stalls. Exact fp32 (_rn, np sum order),
// np.argmax first-max tie-break (ballot/ffs smallest lane, smallest slot).
// ---------------------------------------------------------------------------
template <int CTRL>
__device__ __forceinline__ float dppmaxf(float v) {
  int s = __builtin_amdgcn_update_dpp(0, __float_as_int(v), CTRL, 0xF, 0xF, true);
  return fmaxf(v, __uint_as_float((unsigned)s));
}

__device__ void fps_seg2(const float4* cpt0, const float4* cpt1, int* out0,
                         int* out1, const int* init1, float* dstate,
                         int* fstate, int b0, int b1, int t0, int tcnt,
                         int lane) {
  float px0[8], py0[8], pz0[8], d0[8];
  float px1[8], py1[8], pz1[8], d1[8];
  int base = lane * 8;
#pragma unroll
  for (int j = 0; j < 8; ++j) {
    int p = base + j;
    int pe = p < 500 ? p : 0;  // invalid slots duplicate point 0
    float4 c = cpt0[pe];
    px0[j] = c.x; py0[j] = c.y; pz0[j] = c.z;
    c = cpt1[pe];
    px1[j] = c.x; py1[j] = c.y; pz1[j] = c.z;
  }
  int f0, f1;
  if (t0 == 0) {
#pragma unroll
    for (int j = 0; j < 8; ++j) { d0[j] = 1e10f; d1[j] = 1e10f; }
    f0 = init1[b0];
    f1 = init1[b1];
  } else {
#pragma unroll
    for (int j = 0; j < 8; ++j) {
      d0[j] = dstate[(b0 * 64 + lane) * 8 + j];
      d1[j] = dstate[(b1 * 64 + lane) * 8 + j];
    }
    f0 = fstate[b0];
    f1 = fstate[b1];
  }
  float4 cc = cpt0[f0];
  float cx0 = cc.x, cy0 = cc.y, cz0 = cc.z;
  cc = cpt1[f1];
  float cx1 = cc.x, cy1 = cc.y, cz1 = cc.z;

  int tend = t0 + tcnt;
  for (int t = t0; t < tend; ++t) {
    if (lane == 0) { out0[t] = f0; out1[t] = f1; }
    if (t == 499) return;
#pragma unroll
    for (int j = 0; j < 8; ++j) {
      float dx = __fsub_rn(px0[j], cx0);
      float dy = __fsub_rn(py0[j], cy0);
      float dz = __fsub_rn(pz0[j], cz0);
      float dd = __fadd_rn(__fadd_rn(__fmul_rn(dx, dx), __fmul_rn(dy, dy)),
                           __fmul_rn(dz, dz));
      d0[j] = fminf(d0[j], dd);
      dx = __fsub_rn(px1[j], cx1);
      dy = __fsub_rn(py1[j], cy1);
      dz = __fsub_rn(pz1[j], cz1);
      dd = __fadd_rn(__fadd_rn(__fmul_rn(dx, dx), __fmul_rn(dy, dy)),
                     __fmul_rn(dz, dz));
      d1[j] = fminf(d1[j], dd);
    }
    float lm0 = fmaxf(fmaxf(fmaxf(d0[0], d0[1]), fmaxf(d0[2], d0[3])),
                      fmaxf(fmaxf(d0[4], d0[5]), fmaxf(d0[6], d0[7])));
    float lm1 = fmaxf(fmaxf(fmaxf(d1[0], d1[1]), fmaxf(d1[2], d1[3])),
                      fmaxf(fmaxf(d1[4], d1[5]), fmaxf(d1[6], d1[7])));
    lm0 = dppmaxf<0x111>(lm0); lm1 = dppmaxf<0x111>(lm1);
    lm0 = dppmaxf<0x112>(lm0); lm1 = dppmaxf<0x112>(lm1);
    lm0 = dppmaxf<0x114>(lm0); lm1 = dppmaxf<0x114>(lm1);
    lm0 = dppmaxf<0x118>(lm0); lm1 = dppmaxf<0x118>(lm1);
    lm0 = dppmaxf<0x142>(lm0); lm1 = dppmaxf<0x142>(lm1);
    lm0 = dppmaxf<0x143>(lm0); lm1 = dppmaxf<0x143>(lm1);
    float mf0 = rlf(lm0, 63), mf1 = rlf(lm1, 63);
    int s0 = 8, s1 = 8;
    float sx0 = 0, sy0 = 0, sz0 = 0, sx1 = 0, sy1 = 0, sz1 = 0;
#pragma unroll
    for (int j = 7; j >= 0; --j) {
      bool h0 = (d0[j] == mf0);
      s0 = h0 ? j : s0; sx0 = h0 ? px0[j] : sx0;
      sy0 = h0 ? py0[j] : sy0; sz0 = h0 ? pz0[j] : sz0;
      bool h1 = (d1[j] == mf1);
      s1 = h1 ? j : s1; sx1 = h1 ? px1[j] : sx1;
      sy1 = h1 ? py1[j] : sy1; sz1 = h1 ? pz1[j] : sz1;
    }
    u64 m0 = __ballot(s0 != 8);
    int li0 = (int)__ffsll(m0) - 1;
    f0 = li0 * 8 + __builtin_amdgcn_readlane(s0, li0);
    cx0 = rlf(sx0, li0); cy0 = rlf(sy0, li0); cz0 = rlf(sz0, li0);
    u64 m1 = __ballot(s1 != 8);
    int li1 = (int)__ffsll(m1) - 1;
    f1 = li1 * 8 + __builtin_amdgcn_readlane(s1, li1);
    cx1 = rlf(sx1, li1); cy1 = rlf(sy1, li1); cz1 = rlf(sz1, li1);
  }
#pragma unroll
  for (int j = 0; j < 8; ++j) {
    dstate[(b0 * 64 + lane) * 8 + j] = d0[j];
    dstate[(b1 * 64 + lane) * 8 + j] = d1[j];
  }
  if (lane == 0) { fstate[b0] = f0; fstate[b1] = f1; }
}

// ---------------------------------------------------------------------------
// Barrier-free MFMA GEMM: fragments loaded straight from global (L1/L2 absorb
// the 2x in-tile reuse), register prefetch one K-step ahead, no LDS staging.
// 128x128 tile, 4 waves (wm,wn in {0,1}), each 64x64 via 4x4 of 16x16x32.
// Frag layout: lane(mrow,quad) of wave reads row base + (k0+quad*8), 16 B.
// mode 0: plain rows; mode 2: direct concat (x[r] at lda..lda+2);
// mode 4: stage-C permuted gather (b=r>>9, p=r&511 clamp<500;
//         A row b*500+idx1[b*500+p], x at b*500+p).
// act: 0 none, 1 relu, 2 relu + per-batch col max -> atomicMax (512 r/b).
// ---------------------------------------------------------------------------
__device__ __forceinline__ bf16x8 load_afrag(const u16* ar, int c, int lda,
                                             const float* xr, int mode) {
  if (c + 8 <= lda) return *(const bf16x8*)(ar + c);
  bf16x8 v = {0, 0, 0, 0, 0, 0, 0, 0};
#pragma unroll
  for (int j = 0; j < 8; ++j) {
    int k = c + j;
    u16 vv = 0;
    if (k < lda) vv = ar[k];
    else if (mode != 0 && k < lda + 3) vv = f2bf(xr[k - lda]);
    v[j] = (short)vv;
  }
  return v;
}

__device__ __forceinline__ void gemm_body(
    const u16* __restrict__ A, int lda, const float* __restrict__ X,
    const int* __restrict__ idx, int mode, const u16* __restrict__ Wb,
    int ldw, const float* __restrict__ bias, u16* __restrict__ C, int ldc,
    int Kp, int N, int act, float* __restrict__ outf, int bx, int by,
    float* red, int t) {
  const int m0 = bx * 128, n0 = by * 128;
  const int w = t >> 6, lane = t & 63;
  const int mrow = lane & 15, quad = lane >> 4;
  const int wm = w >> 1, wn = w & 1;

  const u16* ar[4];
  const float* xr[4];
#pragma unroll
  for (int mi = 0; mi < 4; ++mi) {
    int gr = m0 + wm * 64 + mi * 16 + mrow;
    if (mode == 4) {
      int b = gr >> 9;
      int p = gr & 511;
      int pe = (p < 500) ? p : 0;
      int s = idx[b * 500 + pe];
      ar[mi] = A + ((size_t)b * 500 + s) * lda;
      xr[mi] = X + ((size_t)b * 500 + pe) * 3;
    } else {
      ar[mi] = A + (size_t)gr * lda;
      xr[mi] = X + (size_t)gr * 3;
    }
  }
  const u16* wr[4];
#pragma unroll
  for (int ni = 0; ni < 4; ++ni)
    wr[ni] = Wb + (size_t)(n0 + wn * 64 + ni * 16 + mrow) * ldw;

  f32x4 acc[4][4];
  const f32x4 fz = {0.f, 0.f, 0.f, 0.f};
#pragma unroll
  for (int i = 0; i < 4; ++i)
#pragma unroll
    for (int j = 0; j < 4; ++j) acc[i][j] = fz;

  const int cq = quad * 8;
  bf16x8 a_cur[4], b_cur[4];
#pragma unroll
  for (int mi = 0; mi < 4; ++mi)
    a_cur[mi] = load_afrag(ar[mi], cq, lda, xr[mi], mode);
#pragma unroll
  for (int ni = 0; ni < 4; ++ni) b_cur[ni] = *(const bf16x8*)(wr[ni] + cq);

  for (int k0 = 0; k0 < Kp; k0 += 32) {
    int kn = (k0 + 32 < Kp) ? (k0 + 32) : k0;  // last prefetch: dummy reload
    int cn = kn + cq;
    bf16x8 a_nxt[4], b_nxt[4];
#pragma unroll
    for (int mi = 0; mi < 4; ++mi)
      a_nxt[mi] = load_afrag(ar[mi], cn, lda, xr[mi], mode);
#pragma unroll
    for (int ni = 0; ni < 4; ++ni) b_nxt[ni] = *(const bf16x8*)(wr[ni] + cn);
#pragma unroll
    for (int mi = 0; mi < 4; ++mi)
#pragma unroll
      for (int ni = 0; ni < 4; ++ni)
        acc[mi][ni] = __builtin_amdgcn_mfma_f32_16x16x32_bf16(
            a_cur[mi], b_cur[ni], acc[mi][ni], 0, 0, 0);
#pragma unroll
    for (int i = 0; i < 4; ++i) { a_cur[i] = a_nxt[i]; b_cur[i] = b_nxt[i]; }
  }

  if (act < 2) {
#pragma unroll
    for (int ni = 0; ni < 4; ++ni) {
      int col = n0 + wn * 64 + ni * 16 + mrow;
      if (col >= N) continue;
      float bv = bias[col];
#pragma unroll
      for (int mi = 0; mi < 4; ++mi)
#pragma unroll
        for (int r = 0; r < 4; ++r) {
          int grow = m0 + wm * 64 + mi * 16 + quad * 4 + r;
          float v = acc[mi][ni][r] + bv;
          if (act == 1) v = fmaxf(v, 0.f);
          C[(size_t)grow * ldc + col] = f2bf(v);
        }
    }
  } else {
#pragma unroll
    for (int ni = 0; ni < 4; ++ni) {
      int col = n0 + wn * 64 + ni * 16 + mrow;
      float bv = (col < N) ? bias[col] : 0.f;
      float mx = 0.f;
#pragma unroll
      for (int mi = 0; mi < 4; ++mi)
#pragma unroll
        for (int r = 0; r < 4; ++r) {
          int grow = m0 + wm * 64 + mi * 16 + quad * 4 + r;
          float v = fmaxf(acc[mi][ni][r] + bv, 0.f);
          if ((grow & 511) < 500) mx = fmaxf(mx, v);
        }
      mx = fmaxf(mx, __shfl_xor(mx, 16, 64));
      mx = fmaxf(mx, __shfl_xor(mx, 32, 64));
      if (quad == 0) red[wm * 128 + wn * 64 + ni * 16 + mrow] = mx;
    }
    __syncthreads();
    if (t < 128) {
      int col = n0 + t;
      if (col < N) {
        float m = fmaxf(red[t], red[128 + t]);
        int b = m0 >> 9;
        atomicMax((unsigned*)&outf[b * 512 + col], __float_as_uint(m));
      }
    }
  }
}

__global__ __launch_bounds__(256) void gemm_mfma(
    const u16* __restrict__ A, int lda, const float* __restrict__ X,
    const int* __restrict__ idx, int mode, const u16* __restrict__ Wb,
    int ldw, const float* __restrict__ bias, u16* __restrict__ C, int ldc,
    int Kp, int N, int act, float* __restrict__ outf) {
  __shared__ __align__(16) float red[256];
  gemm_body(A, lda, X, idx, mode, Wb, ldw, bias, C, ldc, Kp, N, act, outf,
            blockIdx.x, blockIdx.y, red, threadIdx.x);
}

// GEMM + FPS segment fused; FPS blocks FIRST (0..63), two batches per block
__global__ __launch_bounds__(256) void gemm_fps(
    const u16* __restrict__ A, int lda, const float* __restrict__ X, int mode,
    const u16* __restrict__ Wb, int ldw, const float* __restrict__ bias,
    u16* __restrict__ C, int ldc, int Kp, int N, int act, int gx,
    const float* __restrict__ x, const int* __restrict__ init1,
    int* __restrict__ idx1, float* __restrict__ dstate,
    int* __restrict__ fstate, int t0, int tcnt) {
  __shared__ __align__(16) float4 smem[1024];  // 2 x 512 centroids / red
  int bid = blockIdx.x;
  int t = threadIdx.x;
  if (bid < 64) {
    int b0 = bid * 2, b1 = bid * 2 + 1;
    float4* cpt0 = smem;
    float4* cpt1 = smem + 512;
    const float* xb0 = x + (size_t)b0 * 1500;
    const float* xb1 = x + (size_t)b1 * 1500;
    for (int p = t; p < 500; p += 256) {
      cpt0[p] = make_float4(xb0[p * 3], xb0[p * 3 + 1], xb0[p * 3 + 2], 0.f);
      cpt1[p] = make_float4(xb1[p * 3], xb1[p * 3 + 1], xb1[p * 3 + 2], 0.f);
    }
    __syncthreads();
    if (t < 64)
      fps_seg2(cpt0, cpt1, idx1 + b0 * 500, idx1 + b1 * 500, init1, dstate,
               fstate, b0, b1, t0, tcnt, t);
  } else {
    int g = bid - 64;
    int by = g / gx, bx = g - by * gx;
    gemm_body(A, lda, X, nullptr, mode, Wb, ldw, bias, C, ldc, Kp, N, act,
              nullptr, bx, by, (float*)smem, t);
  }
}

// ---------------------------------------------------------------------------
// prep (+ FPS segment 0): weight converts (K,N zero-padded) + zero + feat
// ---------------------------------------------------------------------------
struct PrepArgs {
  const float* wsrc[8];
  u16* wdst[8];
  int wN[8], wK[8], wKp[8];
  int wstart[9];
};

__global__ __launch_bounds__(256) void prep_kernel(
    PrepArgs pa, const float* __restrict__ x, const float* __restrict__ cW,
    const float* __restrict__ cb, u16* __restrict__ feat,
    float* __restrict__ outf, const int* __restrict__ init1,
    int* __restrict__ idx1, float* __restrict__ dstate,
    int* __restrict__ fstate, int tcnt) {
  __shared__ float4 cpt[1024];
  int bid = blockIdx.x;
  int t = threadIdx.x;
  if (bid < 64) {
    int b0 = bid * 2, b1 = bid * 2 + 1;
    const float* xb0 = x + (size_t)b0 * 1500;
    const float* xb1 = x + (size_t)b1 * 1500;
    for (int p = t; p < 500; p += 256) {
      cpt[p] = make_float4(xb0[p * 3], xb0[p * 3 + 1], xb0[p * 3 + 2], 0.f);
      cpt[512 + p] = make_float4(xb1[p * 3], xb1[p * 3 + 1], xb1[p * 3 + 2], 0.f);
    }
    __syncthreads();
    if (t < 64)
      fps_seg2(cpt, cpt + 512, idx1 + b0 * 500, idx1 + b1 * 500, init1,
               dstate, fstate, b0, b1, 0, tcnt, t);
    return;
  }
  int i = (bid - 64) * 256 + t;
  int S = pa.wstart[8];
  if (i < S) {
    int w = 0;
#pragma unroll
    for (int j = 1; j < 8; ++j)
      if (i >= pa.wstart[j]) w = j;
    int local = i - pa.wstart[w];
    int Kp = pa.wKp[w];
    int n = local / Kp, k = local - n * Kp;
    pa.wdst[w][local] =
        (n < pa.wN[w] && k < pa.wK[w]) ? f2bf(pa.wsrc[w][n * pa.wK[w] + k]) : (u16)0;
  } else if (i < S + 65536) {
    outf[i - S] = 0.f;
  } else {
    int r = i - S - 65536;
    if (r < M_AB) {
      float x0 = x[r * 3], x1 = x[r * 3 + 1], x2 = x[r * 3 + 2];
      float z = x0 * cW[0] + x1 * cW[1] + x2 * cW[2] + cb[0];
      float conf = 1.0f / (1.0f + expf(-z));
      feat[r * 4 + 0] = f2bf(conf);
      feat[r * 4 + 1] = f2bf(x0);
      feat[r * 4 + 2] = f2bf(x1);
      feat[r * 4 + 3] = f2bf(x2);
    }
  }
}

// ---------------------------------------------------------------------------
extern "C" void kernel_launch(void* const* d_in, const int* in_sizes, int n_in,
                              void* d_out, int out_size, void* d_ws,
                              size_t ws_size, hipStream_t stream) {
  const float* x      = (const float*)d_in[0];
  const float* conf_W = (const float*)d_in[1];
  const float* conf_b = (const float*)d_in[2];
  const float* w1     = (const float*)d_in[3];
  const float* b1     = (const float*)d_in[4];
  const float* w2     = (const float*)d_in[5];
  const float* b2     = (const float*)d_in[6];
  const float* pc1_W  = (const float*)d_in[7];
  const float* pc1_b  = (const float*)d_in[8];
  const float* w3     = (const float*)d_in[9];
  const float* b3     = (const float*)d_in[10];
  const float* w4     = (const float*)d_in[11];
  const float* b4     = (const float*)d_in[12];
  const float* pc2_W  = (const float*)d_in[13];
  const float* pc2_b  = (const float*)d_in[14];
  const float* w5     = (const float*)d_in[15];
  const float* b5     = (const float*)d_in[16];
  const float* w6     = (const float*)d_in[17];
  const float* b6     = (const float*)d_in[18];
  const int* init1    = (const int*)d_in[20];

  char* ws = (char*)d_ws;
  u16* feat = (u16*)(ws + 0);
  u16* l2b  = (u16*)(ws + 0);
  u16* l4b  = (u16*)(ws + 0);
  u16* l6u  = (u16*)(ws + 0);
  u16* l1b  = (u16*)(ws + OFF_ARENA_B);
  u16* l3b  = (u16*)(ws + OFF_ARENA_B);
  u16* l5b  = (u16*)(ws + OFF_ARENA_B);
  u16* l7b  = (u16*)(ws + OFF_ARENA_B);
  int* idx1 = (int*)(ws + OFF_IDX1);
  float* dstate = (float*)(ws + OFF_FPSD);
  int* fstate   = (int*)(ws + OFF_FPSI);
  u16* wb   = (u16*)(ws + OFF_WB);
  float* outf = (float*)d_out;  // 128x512 fp32, accumulated via atomicMax

  PrepArgs pa;
  const float* srcs[8] = {w1, w2, pc1_W, w3, w4, pc2_W, w5, w6};
  int Ns[8]  = {64, 256, 256, 256, 384, 384, 384, 512};
  int Nps[8] = {128, 256, 256, 256, 384, 384, 384, 512};
  int Ks[8]  = {4, 64, 256, 259, 256, 384, 387, 384};
  int Kps[8] = {64, 64, 256, 320, 256, 384, 448, 384};
  u16* WBp[8];
  int cum = 0;
  for (int i = 0; i < 8; ++i) {
    pa.wsrc[i] = srcs[i];
    pa.wdst[i] = WBp[i] = wb + cum;
    pa.wN[i] = Ns[i];
    pa.wK[i] = Ks[i];
    pa.wKp[i] = Kps[i];
    pa.wstart[i] = cum;
    cum += Nps[i] * Kps[i];
  }
  pa.wstart[8] = cum;
  int total = cum + 65536 + M_AB;

  // FPS split over 7 dispatches: 60,40,50,70,85,90,105 iters (sum 500)
  prep_kernel<<<64 + (total + 255) / 256, 256, 0, stream>>>(
      pa, x, conf_W, conf_b, feat, outf, init1, idx1, dstate, fstate, 60);
  // stage A
  gemm_fps<<<64 + 500, 256, 0, stream>>>(feat, 4, x, 0, WBp[0], 64,
      b1, l1b, 64, 64, 64, 1, 500, x, init1, idx1, dstate, fstate, 60, 40);
  gemm_fps<<<64 + 1000, 256, 0, stream>>>(l1b, 64, x, 0, WBp[1], 64,
      b2, l2b, 256, 64, 256, 1, 500, x, init1, idx1, dstate, fstate, 100, 50);
  gemm_fps<<<64 + 1000, 256, 0, stream>>>(l2b, 256, x, 0, WBp[2], 256,
      pc1_b, l3b, 256, 256, 256, 0, 500, x, init1, idx1, dstate, fstate, 150, 70);
  // stage B — unpermuted rows (no idx1 dependency)
  gemm_fps<<<64 + 1000, 256, 0, stream>>>(l3b, 256, x, 2, WBp[3], 320,
      b3, l4b, 256, 320, 256, 1, 500, x, init1, idx1, dstate, fstate, 220, 85);
  gemm_fps<<<64 + 1500, 256, 0, stream>>>(l4b, 256, x, 0, WBp[4], 256,
      b4, l5b, 384, 256, 384, 1, 500, x, init1, idx1, dstate, fstate, 305, 90);
  gemm_fps<<<64 + 1500, 256, 0, stream>>>(l5b, 384, x, 0, WBp[5], 384,
      pc2_b, l6u, 384, 384, 384, 0, 500, x, init1, idx1, dstate, fstate, 395, 105);
  // stage C — permutation applied here (mode 4), then final layer + max
  gemm_mfma<<<dim3(512, 3), 256, 0, stream>>>(l6u, 384, x, idx1, 4,
      WBp[6], 448, b5, l7b, 384, 448, 384, 1, nullptr);
  gemm_mfma<<<dim3(512, 4), 256, 0, stream>>>(l7b, 384, nullptr, nullptr, 0,
      WBp[7], 384, b6, nullptr, 0, 384, 512, 2, outf);
}

// Round 12
// 522.088 us; speedup vs baseline: 1.2556x; 1.2556x over previous
//
#include <hip/hip_runtime.h>

typedef unsigned short u16;
typedef short bf16x8 __attribute__((ext_vector_type(8)));   // 8 bf16 (4 VGPRs)
typedef float f32x4 __attribute__((ext_vector_type(4)));
typedef unsigned short us8 __attribute__((ext_vector_type(8)));
typedef unsigned long long u64;

__device__ __forceinline__ float bf2f(u16 u) {
  return __uint_as_float(((unsigned)u) << 16);
}
__device__ __forceinline__ u16 f2bf(float f) {
  unsigned u = __float_as_uint(f);
  u += 0x7fffu + ((u >> 16) & 1u);  // RNE (no NaNs in this workload)
  return (u16)(u >> 16);
}
__device__ __forceinline__ float rlf(float v, int l) {
  return __uint_as_float((unsigned)__builtin_amdgcn_readlane(__float_as_int(v), l));
}
// async global(16B/lane) -> LDS(wave-uniform base + lane*16) [m97-verified]
__device__ __forceinline__ void gload16(const u16* g, u16* l) {
  __builtin_amdgcn_global_load_lds(
      (const __attribute__((address_space(1))) void*)g,
      (__attribute__((address_space(3))) void*)l, 16, 0, 0);
}

// ---------------------------------------------------------------------------
// B=128, N=500. Stages A/B on 64000 unpermuted rows (permutation deferred to
// stage C). Stage C padded to 512 rows/batch -> 65536.
// ---------------------------------------------------------------------------
#define M_AB 64000
#define M_C 65536

#define OFF_ARENA_B 49152000u
#define OFF_IDX1 149815296u   // 128x500 int
#define OFF_FPSD 150071296u   // fps dist state
#define OFF_FPSI 150333440u   // fps fidx state
#define OFF_WB   150583296u   // bf16 weight arena (N,K padded)

// ---------------------------------------------------------------------------
// FPS: two independent batches per wave (chains interleave, fill stalls).
// Exact fp32 (_rn, np sum order), np.argmax first-max tie-break.
// ---------------------------------------------------------------------------
template <int CTRL>
__device__ __forceinline__ float dppmaxf(float v) {
  int s = __builtin_amdgcn_update_dpp(0, __float_as_int(v), CTRL, 0xF, 0xF, true);
  return fmaxf(v, __uint_as_float((unsigned)s));
}

__device__ void fps_seg2(const float4* cpt0, const float4* cpt1, int* out0,
                         int* out1, const int* init1, float* dstate,
                         int* fstate, int b0, int b1, int t0, int tcnt,
                         int lane) {
  float px0[8], py0[8], pz0[8], d0[8];
  float px1[8], py1[8], pz1[8], d1[8];
  int base = lane * 8;
#pragma unroll
  for (int j = 0; j < 8; ++j) {
    int p = base + j;
    int pe = p < 500 ? p : 0;  // invalid slots duplicate point 0
    float4 c = cpt0[pe];
    px0[j] = c.x; py0[j] = c.y; pz0[j] = c.z;
    c = cpt1[pe];
    px1[j] = c.x; py1[j] = c.y; pz1[j] = c.z;
  }
  int f0, f1;
  if (t0 == 0) {
#pragma unroll
    for (int j = 0; j < 8; ++j) { d0[j] = 1e10f; d1[j] = 1e10f; }
    f0 = init1[b0];
    f1 = init1[b1];
  } else {
#pragma unroll
    for (int j = 0; j < 8; ++j) {
      d0[j] = dstate[(b0 * 64 + lane) * 8 + j];
      d1[j] = dstate[(b1 * 64 + lane) * 8 + j];
    }
    f0 = fstate[b0];
    f1 = fstate[b1];
  }
  float4 cc = cpt0[f0];
  float cx0 = cc.x, cy0 = cc.y, cz0 = cc.z;
  cc = cpt1[f1];
  float cx1 = cc.x, cy1 = cc.y, cz1 = cc.z;

  int tend = t0 + tcnt;
  for (int t = t0; t < tend; ++t) {
    if (lane == 0) { out0[t] = f0; out1[t] = f1; }
    if (t == 499) return;
#pragma unroll
    for (int j = 0; j < 8; ++j) {
      float dx = __fsub_rn(px0[j], cx0);
      float dy = __fsub_rn(py0[j], cy0);
      float dz = __fsub_rn(pz0[j], cz0);
      float dd = __fadd_rn(__fadd_rn(__fmul_rn(dx, dx), __fmul_rn(dy, dy)),
                           __fmul_rn(dz, dz));
      d0[j] = fminf(d0[j], dd);
      dx = __fsub_rn(px1[j], cx1);
      dy = __fsub_rn(py1[j], cy1);
      dz = __fsub_rn(pz1[j], cz1);
      dd = __fadd_rn(__fadd_rn(__fmul_rn(dx, dx), __fmul_rn(dy, dy)),
                     __fmul_rn(dz, dz));
      d1[j] = fminf(d1[j], dd);
    }
    float lm0 = fmaxf(fmaxf(fmaxf(d0[0], d0[1]), fmaxf(d0[2], d0[3])),
                      fmaxf(fmaxf(d0[4], d0[5]), fmaxf(d0[6], d0[7])));
    float lm1 = fmaxf(fmaxf(fmaxf(d1[0], d1[1]), fmaxf(d1[2], d1[3])),
                      fmaxf(fmaxf(d1[4], d1[5]), fmaxf(d1[6], d1[7])));
    lm0 = dppmaxf<0x111>(lm0); lm1 = dppmaxf<0x111>(lm1);
    lm0 = dppmaxf<0x112>(lm0); lm1 = dppmaxf<0x112>(lm1);
    lm0 = dppmaxf<0x114>(lm0); lm1 = dppmaxf<0x114>(lm1);
    lm0 = dppmaxf<0x118>(lm0); lm1 = dppmaxf<0x118>(lm1);
    lm0 = dppmaxf<0x142>(lm0); lm1 = dppmaxf<0x142>(lm1);
    lm0 = dppmaxf<0x143>(lm0); lm1 = dppmaxf<0x143>(lm1);
    float mf0 = rlf(lm0, 63), mf1 = rlf(lm1, 63);
    int s0 = 8, s1 = 8;
    float sx0 = 0, sy0 = 0, sz0 = 0, sx1 = 0, sy1 = 0, sz1 = 0;
#pragma unroll
    for (int j = 7; j >= 0; --j) {
      bool h0 = (d0[j] == mf0);
      s0 = h0 ? j : s0; sx0 = h0 ? px0[j] : sx0;
      sy0 = h0 ? py0[j] : sy0; sz0 = h0 ? pz0[j] : sz0;
      bool h1 = (d1[j] == mf1);
      s1 = h1 ? j : s1; sx1 = h1 ? px1[j] : sx1;
      sy1 = h1 ? py1[j] : sy1; sz1 = h1 ? pz1[j] : sz1;
    }
    u64 m0 = __ballot(s0 != 8);
    int li0 = (int)__ffsll(m0) - 1;
    f0 = li0 * 8 + __builtin_amdgcn_readlane(s0, li0);
    cx0 = rlf(sx0, li0); cy0 = rlf(sy0, li0); cz0 = rlf(sz0, li0);
    u64 m1 = __ballot(s1 != 8);
    int li1 = (int)__ffsll(m1) - 1;
    f1 = li1 * 8 + __builtin_amdgcn_readlane(s1, li1);
    cx1 = rlf(sx1, li1); cy1 = rlf(sy1, li1); cz1 = rlf(sz1, li1);
  }
#pragma unroll
  for (int j = 0; j < 8; ++j) {
    dstate[(b0 * 64 + lane) * 8 + j] = d0[j];
    dstate[(b1 * 64 + lane) * 8 + j] = d1[j];
  }
  if (lane == 0) { fstate[b0] = f0; fstate[b1] = f1; }
}

// ---------------------------------------------------------------------------
// MFMA GEMM body (round-10 proven structure): 128x128 tile, BK=64,
// global_load_lds staging, XOR-swizzled unpadded LDS [128][64]. 4 waves,
// each 64x64 (4x4 of 16x16x32).
// mode 0: plain rows; mode 2: direct concat (x[r] at lda..lda+2);
// mode 4: stage-C permuted gather (b=r>>9, p=r&511 clamp<500;
//         A row b*500+idx1[b*500+p], x at b*500+p).
// act: 0 none, 1 relu, 2 relu + per-batch col max -> atomicMax (512 r/b).
// ---------------------------------------------------------------------------
#define SMEM_BYTES (16384 * 2 + 1024)

__device__ __forceinline__ void gemm_body(
    const u16* __restrict__ A, int lda, const float* __restrict__ X,
    const int* __restrict__ idx, int mode, const u16* __restrict__ Wb,
    int ldw, const float* __restrict__ bias, u16* __restrict__ C, int ldc,
    int Kp, int N, int act, float* __restrict__ outf, int bx, int by,
    char* smem, int t) {
  u16* lA = (u16*)smem;
  u16* lB = (u16*)(smem + 16384);
  float* red = (float*)(smem + 32768);

  const int m0 = bx * 128, n0 = by * 128;
  const int w = t >> 6, lane = t & 63;
  const int mrow = lane & 15, quad = lane >> 4;
  const int wm = w >> 1, wn = w & 1;

  const int lrow8 = lane >> 3;
  const int sseg = (lane & 7) ^ lrow8;

  const u16* arow[4];
  const u16* wrow[4];
#pragma unroll
  for (int i = 0; i < 4; ++i) {
    int gr = m0 + w * 32 + i * 8 + lrow8;
    if (mode == 4) {
      int b = gr >> 9;
      int p = gr & 511;
      int pe = (p < 500) ? p : 0;
      int s = idx[b * 500 + pe];
      arow[i] = A + ((size_t)b * 500 + s) * lda;
    } else {
      arow[i] = A + (size_t)gr * lda;
    }
    wrow[i] = Wb + (size_t)(n0 + w * 32 + i * 8 + lrow8) * ldw;
  }
  // fallback (tail-chunk) coords: thread t covers row t>>1, segs (t&1)*4..+4
  const int fr = t >> 1;
  const int fs0 = (t & 1) * 4;
  const u16* faptr;
  const float* fxptr = nullptr;
  {
    int gr = m0 + fr;
    if (mode == 4) {
      int b = gr >> 9;
      int p = gr & 511;
      int pe = (p < 500) ? p : 0;
      int s = idx[b * 500 + pe];
      faptr = A + ((size_t)b * 500 + s) * lda;
      fxptr = X + ((size_t)b * 500 + pe) * 3;
    } else {
      faptr = A + (size_t)gr * lda;
      if (mode == 2) fxptr = X + (size_t)gr * 3;
    }
  }
  const int kfull = lda & ~63;

  f32x4 acc[4][4];
  const f32x4 fz = {0.f, 0.f, 0.f, 0.f};
#pragma unroll
  for (int i = 0; i < 4; ++i)
#pragma unroll
    for (int j = 0; j < 4; ++j) acc[i][j] = fz;

  for (int k0 = 0; k0 < Kp; k0 += 64) {
    __syncthreads();
#pragma unroll
    for (int i = 0; i < 4; ++i)
      gload16(wrow[i] + k0 + sseg * 8, lB + (w * 32 + i * 8) * 64);
    if (k0 < kfull) {
#pragma unroll
      for (int i = 0; i < 4; ++i)
        gload16(arow[i] + k0 + sseg * 8, lA + (w * 32 + i * 8) * 64);
    } else {
#pragma unroll
      for (int s4 = 0; s4 < 4; ++s4) {
        int seg = fs0 + s4;
        us8 v = {0, 0, 0, 0, 0, 0, 0, 0};
        int kb = k0 + seg * 8;
#pragma unroll
        for (int j = 0; j < 8; ++j) {
          int k = kb + j;
          u16 vv = 0;
          if (k < lda) vv = faptr[k];
          else if (mode != 0 && k < lda + 3) vv = f2bf(fxptr[k - lda]);
          v[j] = vv;
        }
        *(us8*)(lA + fr * 64 + (seg ^ (fr & 7)) * 8) = v;
      }
    }
    __syncthreads();

#pragma unroll
    for (int kh = 0; kh < 2; ++kh) {
      bf16x8 af[4], bfv[4];
#pragma unroll
      for (int mi = 0; mi < 4; ++mi) {
        int r = wm * 64 + mi * 16 + mrow;
        af[mi] = *(const bf16x8*)(lA + r * 64 + ((kh * 4 + quad) ^ (r & 7)) * 8);
      }
#pragma unroll
      for (int ni = 0; ni < 4; ++ni) {
        int r = wn * 64 + ni * 16 + mrow;
        bfv[ni] = *(const bf16x8*)(lB + r * 64 + ((kh * 4 + quad) ^ (r & 7)) * 8);
      }
#pragma unroll
      for (int mi = 0; mi < 4; ++mi)
#pragma unroll
        for (int ni = 0; ni < 4; ++ni)
          acc[mi][ni] = __builtin_amdgcn_mfma_f32_16x16x32_bf16(
              af[mi], bfv[ni], acc[mi][ni], 0, 0, 0);
    }
  }

  if (act < 2) {
#pragma unroll
    for (int ni = 0; ni < 4; ++ni) {
      int col = n0 + wn * 64 + ni * 16 + mrow;
      if (col >= N) continue;
      float bv = bias[col];
#pragma unroll
      for (int mi = 0; mi < 4; ++mi)
#pragma unroll
        for (int r = 0; r < 4; ++r) {
          int grow = m0 + wm * 64 + mi * 16 + quad * 4 + r;
          float v = acc[mi][ni][r] + bv;
          if (act == 1) v = fmaxf(v, 0.f);
          C[(size_t)grow * ldc + col] = f2bf(v);
        }
    }
  } else {
#pragma unroll
    for (int ni = 0; ni < 4; ++ni) {
      int col = n0 + wn * 64 + ni * 16 + mrow;
      float bv = (col < N) ? bias[col] : 0.f;
      float mx = 0.f;
#pragma unroll
      for (int mi = 0; mi < 4; ++mi)
#pragma unroll
        for (int r = 0; r < 4; ++r) {
          int grow = m0 + wm * 64 + mi * 16 + quad * 4 + r;
          float v = fmaxf(acc[mi][ni][r] + bv, 0.f);
          if ((grow & 511) < 500) mx = fmaxf(mx, v);
        }
      mx = fmaxf(mx, __shfl_xor(mx, 16, 64));
      mx = fmaxf(mx, __shfl_xor(mx, 32, 64));
      if (quad == 0) red[wm * 128 + wn * 64 + ni * 16 + mrow] = mx;
    }
    __syncthreads();
    if (t < 128) {
      int col = n0 + t;
      if (col < N) {
        float m = fmaxf(red[t], red[128 + t]);
        int b = m0 >> 9;
        atomicMax((unsigned*)&outf[b * 512 + col], __float_as_uint(m));
      }
    }
  }
}

__global__ __launch_bounds__(256) void gemm_mfma(
    const u16* __restrict__ A, int lda, const float* __restrict__ X,
    const int* __restrict__ idx, int mode, const u16* __restrict__ Wb,
    int ldw, const float* __restrict__ bias, u16* __restrict__ C, int ldc,
    int Kp, int N, int act, float* __restrict__ outf) {
  __shared__ __align__(16) char smem[SMEM_BYTES];
  gemm_body(A, lda, X, idx, mode, Wb, ldw, bias, C, ldc, Kp, N, act, outf,
            blockIdx.x, blockIdx.y, smem, threadIdx.x);
}

// GEMM + FPS segment fused; FPS blocks FIRST (0..63), two batches per block
__global__ __launch_bounds__(256) void gemm_fps(
    const u16* __restrict__ A, int lda, const float* __restrict__ X, int mode,
    const u16* __restrict__ Wb, int ldw, const float* __restrict__ bias,
    u16* __restrict__ C, int ldc, int Kp, int N, int act, int gx,
    const float* __restrict__ x, const int* __restrict__ init1,
    int* __restrict__ idx1, float* __restrict__ dstate,
    int* __restrict__ fstate, int t0, int tcnt) {
  __shared__ __align__(16) char smem[SMEM_BYTES];
  int bid = blockIdx.x;
  int t = threadIdx.x;
  if (bid < 64) {
    int b0 = bid * 2, b1 = bid * 2 + 1;
    float4* cpt0 = (float4*)smem;        // 2 x 512 x 16B = 16 KB <= 33 KB
    float4* cpt1 = cpt0 + 512;
    const float* xb0 = x + (size_t)b0 * 1500;
    const float* xb1 = x + (size_t)b1 * 1500;
    for (int p = t; p < 500; p += 256) {
      cpt0[p] = make_float4(xb0[p * 3], xb0[p * 3 + 1], xb0[p * 3 + 2], 0.f);
      cpt1[p] = make_float4(xb1[p * 3], xb1[p * 3 + 1], xb1[p * 3 + 2], 0.f);
    }
    __syncthreads();
    if (t < 64)
      fps_seg2(cpt0, cpt1, idx1 + b0 * 500, idx1 + b1 * 500, init1, dstate,
               fstate, b0, b1, t0, tcnt, t);
  } else {
    int g = bid - 64;
    int by = g / gx, bx = g - by * gx;
    gemm_body(A, lda, X, nullptr, mode, Wb, ldw, bias, C, ldc, Kp, N, act,
              nullptr, bx, by, smem, t);
  }
}

// ---------------------------------------------------------------------------
// prep (+ FPS seg0): 7 weight converts (K,N zero-padded) + zero(outf) +
// fused feat+l1 rows (layer-1 GEMM absorbed: 64 outs from 4 ins, scalar fp32)
// ---------------------------------------------------------------------------
struct PrepArgs {
  const float* wsrc[7];
  u16* wdst[7];
  int wN[7], wK[7], wKp[7];
  int wstart[8];
};

__global__ __launch_bounds__(256) void prep_kernel(
    PrepArgs pa, const float* __restrict__ x, const float* __restrict__ cW,
    const float* __restrict__ cb, const float* __restrict__ w1,
    const float* __restrict__ b1, u16* __restrict__ l1,
    float* __restrict__ outf, const int* __restrict__ init1,
    int* __restrict__ idx1, float* __restrict__ dstate,
    int* __restrict__ fstate, int tcnt) {
  __shared__ float4 cpt[1024];
  int bid = blockIdx.x;
  int t = threadIdx.x;
  if (bid < 64) {
    int b0 = bid * 2, b1i = bid * 2 + 1;
    const float* xb0 = x + (size_t)b0 * 1500;
    const float* xb1 = x + (size_t)b1i * 1500;
    for (int p = t; p < 500; p += 256) {
      cpt[p] = make_float4(xb0[p * 3], xb0[p * 3 + 1], xb0[p * 3 + 2], 0.f);
      cpt[512 + p] = make_float4(xb1[p * 3], xb1[p * 3 + 1], xb1[p * 3 + 2], 0.f);
    }
    __syncthreads();
    if (t < 64)
      fps_seg2(cpt, cpt + 512, idx1 + b0 * 500, idx1 + b1i * 500, init1,
               dstate, fstate, b0, b1i, 0, tcnt, t);
    return;
  }
  int i = (bid - 64) * 256 + t;
  int S = pa.wstart[7];
  if (i < S) {
    int w = 0;
#pragma unroll
    for (int j = 1; j < 7; ++j)
      if (i >= pa.wstart[j]) w = j;
    int local = i - pa.wstart[w];
    int Kp = pa.wKp[w];
    int n = local / Kp, k = local - n * Kp;
    pa.wdst[w][local] =
        (n < pa.wN[w] && k < pa.wK[w]) ? f2bf(pa.wsrc[w][n * pa.wK[w] + k]) : (u16)0;
  } else if (i < S + 65536) {
    outf[i - S] = 0.f;
  } else {
    int r = i - S - 65536;
    if (r < M_AB) {
      float x0 = x[r * 3], x1 = x[r * 3 + 1], x2 = x[r * 3 + 2];
      float z = x0 * cW[0] + x1 * cW[1] + x2 * cW[2] + cb[0];
      float conf = 1.0f / (1.0f + expf(-z));
      // layer 1 fused: l1[r][n] = relu(conf*w1[n][0]+x0*w1[n][1]+x1*w1[n][2]
      //                                +x2*w1[n][3]+b1[n]), 64 outs, fp32
      u16* dst = l1 + (size_t)r * 64;
#pragma unroll
      for (int n8 = 0; n8 < 64; n8 += 8) {
        us8 v;
#pragma unroll
        for (int j = 0; j < 8; ++j) {
          const float* wr = w1 + (n8 + j) * 4;
          float a = fmaf(conf, wr[0], b1[n8 + j]);
          a = fmaf(x0, wr[1], a);
          a = fmaf(x1, wr[2], a);
          a = fmaf(x2, wr[3], a);
          v[j] = f2bf(fmaxf(a, 0.f));
        }
        *(us8*)(dst + n8) = v;
      }
    }
  }
}

// ---------------------------------------------------------------------------
extern "C" void kernel_launch(void* const* d_in, const int* in_sizes, int n_in,
                              void* d_out, int out_size, void* d_ws,
                              size_t ws_size, hipStream_t stream) {
  const float* x      = (const float*)d_in[0];
  const float* conf_W = (const float*)d_in[1];
  const float* conf_b = (const float*)d_in[2];
  const float* w1     = (const float*)d_in[3];
  const float* b1     = (const float*)d_in[4];
  const float* w2     = (const float*)d_in[5];
  const float* b2     = (const float*)d_in[6];
  const float* pc1_W  = (const float*)d_in[7];
  const float* pc1_b  = (const float*)d_in[8];
  const float* w3     = (const float*)d_in[9];
  const float* b3     = (const float*)d_in[10];
  const float* w4     = (const float*)d_in[11];
  const float* b4     = (const float*)d_in[12];
  const float* pc2_W  = (const float*)d_in[13];
  const float* pc2_b  = (const float*)d_in[14];
  const float* w5     = (const float*)d_in[15];
  const float* b5     = (const float*)d_in[16];
  const float* w6     = (const float*)d_in[17];
  const float* b6     = (const float*)d_in[18];
  const int* init1    = (const int*)d_in[20];

  char* ws = (char*)d_ws;
  u16* l2b  = (u16*)(ws + 0);
  u16* l4b  = (u16*)(ws + 0);
  u16* l6u  = (u16*)(ws + 0);
  u16* l1b  = (u16*)(ws + OFF_ARENA_B);
  u16* l3b  = (u16*)(ws + OFF_ARENA_B);
  u16* l5b  = (u16*)(ws + OFF_ARENA_B);
  u16* l7b  = (u16*)(ws + OFF_ARENA_B);
  int* idx1 = (int*)(ws + OFF_IDX1);
  float* dstate = (float*)(ws + OFF_FPSD);
  int* fstate   = (int*)(ws + OFF_FPSI);
  u16* wb   = (u16*)(ws + OFF_WB);
  float* outf = (float*)d_out;  // 128x512 fp32, accumulated via atomicMax

  // 7 weights (w1 handled in prep): w2, pc1, w3, w4, pc2, w5, w6
  PrepArgs pa;
  const float* srcs[7] = {w2, pc1_W, w3, w4, pc2_W, w5, w6};
  int Ns[7]  = {256, 256, 256, 384, 384, 384, 512};
  int Nps[7] = {256, 256, 256, 384, 384, 384, 512};
  int Ks[7]  = {64, 256, 259, 256, 384, 387, 384};
  int Kps[7] = {64, 256, 320, 256, 384, 448, 384};
  u16* WBp[7];
  int cum = 0;
  for (int i = 0; i < 7; ++i) {
    pa.wsrc[i] = srcs[i];
    pa.wdst[i] = WBp[i] = wb + cum;
    pa.wN[i] = Ns[i];
    pa.wK[i] = Ks[i];
    pa.wKp[i] = Kps[i];
    pa.wstart[i] = cum;
    cum += Nps[i] * Kps[i];
  }
  pa.wstart[7] = cum;
  int total = cum + 65536 + M_AB;

  // FPS split over 6 dispatches: 40,50,70,100,110,130 (sum 500); done pre-C1
  prep_kernel<<<64 + (total + 255) / 256, 256, 0, stream>>>(
      pa, x, conf_W, conf_b, w1, b1, l1b, outf, init1, idx1, dstate, fstate, 40);
  // stage A (A1 absorbed into prep)
  gemm_fps<<<64 + 1000, 256, 0, stream>>>(l1b, 64, x, 0, WBp[0], 64,
      b2, l2b, 256, 64, 256, 1, 500, x, init1, idx1, dstate, fstate, 40, 50);
  gemm_fps<<<64 + 1000, 256, 0, stream>>>(l2b, 256, x, 0, WBp[1], 256,
      pc1_b, l3b, 256, 256, 256, 0, 500, x, init1, idx1, dstate, fstate, 90, 70);
  // stage B — unpermuted rows (no idx1 dependency)
  gemm_fps<<<64 + 1000, 256, 0, stream>>>(l3b, 256, x, 2, WBp[2], 320,
      b3, l4b, 256, 320, 256, 1, 500, x, init1, idx1, dstate, fstate, 160, 100);
  gemm_fps<<<64 + 1500, 256, 0, stream>>>(l4b, 256, x, 0, WBp[3], 256,
      b4, l5b, 384, 256, 384, 1, 500, x, init1, idx1, dstate, fstate, 260, 110);
  gemm_fps<<<64 + 1500, 256, 0, stream>>>(l5b, 384, x, 0, WBp[4], 384,
      pc2_b, l6u, 384, 384, 384, 0, 500, x, init1, idx1, dstate, fstate, 370, 130);
  // stage C — permutation applied here (mode 4), then final layer + max
  gemm_mfma<<<dim3(512, 3), 256, 0, stream>>>(l6u, 384, x, idx1, 4,
      WBp[5], 448, b5, l7b, 384, 448, 384, 1, nullptr);
  gemm_mfma<<<dim3(512, 4), 256, 0, stream>>>(l7b, 384, nullptr, nullptr, 0,
      WBp[6], 384, b6, nullptr, 0, 384, 512, 2, outf);
}

// Round 13
// 413.071 us; speedup vs baseline: 1.5869x; 1.2639x over previous
//
#include <hip/hip_runtime.h>

typedef unsigned short u16;
typedef short bf16x8 __attribute__((ext_vector_type(8)));   // 8 bf16 (4 VGPRs)
typedef float f32x4 __attribute__((ext_vector_type(4)));
typedef unsigned short us8 __attribute__((ext_vector_type(8)));
typedef unsigned long long u64;

__device__ __forceinline__ float bf2f(u16 u) {
  return __uint_as_float(((unsigned)u) << 16);
}
__device__ __forceinline__ u16 f2bf(float f) {
  unsigned u = __float_as_uint(f);
  u += 0x7fffu + ((u >> 16) & 1u);  // RNE (no NaNs in this workload)
  return (u16)(u >> 16);
}
__device__ __forceinline__ float rlf(float v, int l) {
  return __uint_as_float((unsigned)__builtin_amdgcn_readlane(__float_as_int(v), l));
}
// async global(16B/lane) -> LDS(wave-uniform base + lane*16) [m97-verified]
__device__ __forceinline__ void gload16(const u16* g, u16* l) {
  __builtin_amdgcn_global_load_lds(
      (const __attribute__((address_space(1))) void*)g,
      (__attribute__((address_space(3))) void*)l, 16, 0, 0);
}

// ---------------------------------------------------------------------------
// B=128, N=500. Stages A/B on 64000 unpermuted rows (permutation deferred to
// stage C). Stage C padded to 512 rows/batch -> 65536.
// ---------------------------------------------------------------------------
#define M_AB 64000
#define M_C 65536

#define OFF_ARENA_B 49152000u
#define OFF_IDX1 149815296u   // 128x500 int
#define OFF_FPSD 150071296u   // fps dist state
#define OFF_FPSI 150333440u   // fps fidx state
#define OFF_WB   150583296u   // bf16 weight arena (N,K padded)

// ---------------------------------------------------------------------------
// FPS: SINGLE chain per wave (80-VGPR profile — fused-kernel occupancy is
// set by max over branches; 2-chain variant cost the GEMM half its blocks).
// Parallelism comes from 4 waves/block, one batch each (own SIMD).
// Exact fp32 (_rn, np sum order), np.argmax first-max tie-break.
// ---------------------------------------------------------------------------
template <int CTRL>
__device__ __forceinline__ float dppmaxf(float v) {
  int s = __builtin_amdgcn_update_dpp(0, __float_as_int(v), CTRL, 0xF, 0xF, true);
  return fmaxf(v, __uint_as_float((unsigned)s));
}

__device__ void fps_seg(const float4* cpt, int* out, const int* init1,
                        float* dstate, int* fstate, int b, int t0, int tcnt,
                        int lane) {
  float px[8], py[8], pz[8], dist[8];
  int base = lane * 8;
#pragma unroll
  for (int j = 0; j < 8; ++j) {
    int p = base + j;
    float4 c = cpt[p < 500 ? p : 0];  // invalid slots duplicate point 0
    px[j] = c.x; py[j] = c.y; pz[j] = c.z;
  }
  int fidx;
  if (t0 == 0) {
#pragma unroll
    for (int j = 0; j < 8; ++j) dist[j] = 1e10f;
    fidx = init1[b];
  } else {
#pragma unroll
    for (int j = 0; j < 8; ++j) dist[j] = dstate[(b * 64 + lane) * 8 + j];
    fidx = fstate[b];
  }
  float4 c0 = cpt[fidx];
  float cx = c0.x, cy = c0.y, cz = c0.z;

  int tend = t0 + tcnt;
  for (int t = t0; t < tend; ++t) {
    if (lane == 0) out[t] = fidx;
    if (t == 499) return;
#pragma unroll
    for (int j = 0; j < 8; ++j) {
      float dx = __fsub_rn(px[j], cx);
      float dy = __fsub_rn(py[j], cy);
      float dz = __fsub_rn(pz[j], cz);
      float d = __fadd_rn(__fadd_rn(__fmul_rn(dx, dx), __fmul_rn(dy, dy)),
                          __fmul_rn(dz, dz));
      dist[j] = fminf(dist[j], d);
    }
    float m01 = fmaxf(dist[0], dist[1]), m23 = fmaxf(dist[2], dist[3]);
    float m45 = fmaxf(dist[4], dist[5]), m67 = fmaxf(dist[6], dist[7]);
    float lm = fmaxf(fmaxf(m01, m23), fmaxf(m45, m67));
    lm = dppmaxf<0x111>(lm);
    lm = dppmaxf<0x112>(lm);
    lm = dppmaxf<0x114>(lm);
    lm = dppmaxf<0x118>(lm);
    lm = dppmaxf<0x142>(lm);
    lm = dppmaxf<0x143>(lm);
    float mf = rlf(lm, 63);
    int sel = 8;
    float sx = 0.f, sy = 0.f, sz = 0.f;
#pragma unroll
    for (int j = 7; j >= 0; --j) {
      bool hit = (dist[j] == mf);
      sel = hit ? j : sel;
      sx = hit ? px[j] : sx;
      sy = hit ? py[j] : sy;
      sz = hit ? pz[j] : sz;
    }
    u64 mask = __ballot(sel != 8);
    int li = (int)__ffsll(mask) - 1;  // smallest lane = smallest point range
    fidx = li * 8 + __builtin_amdgcn_readlane(sel, li);
    cx = rlf(sx, li);
    cy = rlf(sy, li);
    cz = rlf(sz, li);
  }
#pragma unroll
  for (int j = 0; j < 8; ++j) dstate[(b * 64 + lane) * 8 + j] = dist[j];
  if (lane == 0) fstate[b] = fidx;
}

// stage 4 batches' centroids into LDS, then each wave runs its own chain
__device__ __forceinline__ void fps_block4(float4* cpt, const float* x,
                                           const int* init1, int* idx1,
                                           float* dstate, int* fstate,
                                           int bid, int t0, int tcnt, int t) {
#pragma unroll
  for (int wv = 0; wv < 4; ++wv) {
    const float* xb = x + (size_t)(bid * 4 + wv) * 1500;
    for (int p = t; p < 500; p += 256)
      cpt[wv * 512 + p] =
          make_float4(xb[p * 3], xb[p * 3 + 1], xb[p * 3 + 2], 0.f);
  }
  __syncthreads();
  int wv = t >> 6;
  int b = bid * 4 + wv;
  fps_seg(cpt + wv * 512, idx1 + b * 500, init1, dstate, fstate, b, t0, tcnt,
          t & 63);
}

// ---------------------------------------------------------------------------
// MFMA GEMM body (round-10 proven structure): 128x128 tile, BK=64,
// global_load_lds staging, XOR-swizzled unpadded LDS [128][64]. 4 waves,
// each 64x64 (4x4 of 16x16x32).
// mode 0: plain rows; mode 2: direct concat (x[r] at lda..lda+2);
// mode 4: stage-C permuted gather (b=r>>9, p=r&511 clamp<500;
//         A row b*500+idx1[b*500+p], x at b*500+p).
// act: 0 none, 1 relu, 2 relu + per-batch col max -> atomicMax (512 r/b).
// ---------------------------------------------------------------------------
#define SMEM_BYTES (16384 * 2 + 1024)  // 33,792 B (also fits 4x512 float4 FPS)

__device__ __forceinline__ void gemm_body(
    const u16* __restrict__ A, int lda, const float* __restrict__ X,
    const int* __restrict__ idx, int mode, const u16* __restrict__ Wb,
    int ldw, const float* __restrict__ bias, u16* __restrict__ C, int ldc,
    int Kp, int N, int act, float* __restrict__ outf, int bx, int by,
    char* smem, int t) {
  u16* lA = (u16*)smem;
  u16* lB = (u16*)(smem + 16384);
  float* red = (float*)(smem + 32768);

  const int m0 = bx * 128, n0 = by * 128;
  const int w = t >> 6, lane = t & 63;
  const int mrow = lane & 15, quad = lane >> 4;
  const int wm = w >> 1, wn = w & 1;

  const int lrow8 = lane >> 3;
  const int sseg = (lane & 7) ^ lrow8;

  const u16* arow[4];
  const u16* wrow[4];
#pragma unroll
  for (int i = 0; i < 4; ++i) {
    int gr = m0 + w * 32 + i * 8 + lrow8;
    if (mode == 4) {
      int b = gr >> 9;
      int p = gr & 511;
      int pe = (p < 500) ? p : 0;
      int s = idx[b * 500 + pe];
      arow[i] = A + ((size_t)b * 500 + s) * lda;
    } else {
      arow[i] = A + (size_t)gr * lda;
    }
    wrow[i] = Wb + (size_t)(n0 + w * 32 + i * 8 + lrow8) * ldw;
  }
  // fallback (tail-chunk) coords: thread t covers row t>>1, segs (t&1)*4..+4
  const int fr = t >> 1;
  const int fs0 = (t & 1) * 4;
  const u16* faptr;
  const float* fxptr = nullptr;
  {
    int gr = m0 + fr;
    if (mode == 4) {
      int b = gr >> 9;
      int p = gr & 511;
      int pe = (p < 500) ? p : 0;
      int s = idx[b * 500 + pe];
      faptr = A + ((size_t)b * 500 + s) * lda;
      fxptr = X + ((size_t)b * 500 + pe) * 3;
    } else {
      faptr = A + (size_t)gr * lda;
      if (mode == 2) fxptr = X + (size_t)gr * 3;
    }
  }
  const int kfull = lda & ~63;

  f32x4 acc[4][4];
  const f32x4 fz = {0.f, 0.f, 0.f, 0.f};
#pragma unroll
  for (int i = 0; i < 4; ++i)
#pragma unroll
    for (int j = 0; j < 4; ++j) acc[i][j] = fz;

  for (int k0 = 0; k0 < Kp; k0 += 64) {
    __syncthreads();
#pragma unroll
    for (int i = 0; i < 4; ++i)
      gload16(wrow[i] + k0 + sseg * 8, lB + (w * 32 + i * 8) * 64);
    if (k0 < kfull) {
#pragma unroll
      for (int i = 0; i < 4; ++i)
        gload16(arow[i] + k0 + sseg * 8, lA + (w * 32 + i * 8) * 64);
    } else {
#pragma unroll
      for (int s4 = 0; s4 < 4; ++s4) {
        int seg = fs0 + s4;
        us8 v = {0, 0, 0, 0, 0, 0, 0, 0};
        int kb = k0 + seg * 8;
#pragma unroll
        for (int j = 0; j < 8; ++j) {
          int k = kb + j;
          u16 vv = 0;
          if (k < lda) vv = faptr[k];
          else if (mode != 0 && k < lda + 3) vv = f2bf(fxptr[k - lda]);
          v[j] = vv;
        }
        *(us8*)(lA + fr * 64 + (seg ^ (fr & 7)) * 8) = v;
      }
    }
    __syncthreads();

#pragma unroll
    for (int kh = 0; kh < 2; ++kh) {
      bf16x8 af[4], bfv[4];
#pragma unroll
      for (int mi = 0; mi < 4; ++mi) {
        int r = wm * 64 + mi * 16 + mrow;
        af[mi] = *(const bf16x8*)(lA + r * 64 + ((kh * 4 + quad) ^ (r & 7)) * 8);
      }
#pragma unroll
      for (int ni = 0; ni < 4; ++ni) {
        int r = wn * 64 + ni * 16 + mrow;
        bfv[ni] = *(const bf16x8*)(lB + r * 64 + ((kh * 4 + quad) ^ (r & 7)) * 8);
      }
#pragma unroll
      for (int mi = 0; mi < 4; ++mi)
#pragma unroll
        for (int ni = 0; ni < 4; ++ni)
          acc[mi][ni] = __builtin_amdgcn_mfma_f32_16x16x32_bf16(
              af[mi], bfv[ni], acc[mi][ni], 0, 0, 0);
    }
  }

  if (act < 2) {
#pragma unroll
    for (int ni = 0; ni < 4; ++ni) {
      int col = n0 + wn * 64 + ni * 16 + mrow;
      if (col >= N) continue;
      float bv = bias[col];
#pragma unroll
      for (int mi = 0; mi < 4; ++mi)
#pragma unroll
        for (int r = 0; r < 4; ++r) {
          int grow = m0 + wm * 64 + mi * 16 + quad * 4 + r;
          float v = acc[mi][ni][r] + bv;
          if (act == 1) v = fmaxf(v, 0.f);
          C[(size_t)grow * ldc + col] = f2bf(v);
        }
    }
  } else {
#pragma unroll
    for (int ni = 0; ni < 4; ++ni) {
      int col = n0 + wn * 64 + ni * 16 + mrow;
      float bv = (col < N) ? bias[col] : 0.f;
      float mx = 0.f;
#pragma unroll
      for (int mi = 0; mi < 4; ++mi)
#pragma unroll
        for (int r = 0; r < 4; ++r) {
          int grow = m0 + wm * 64 + mi * 16 + quad * 4 + r;
          float v = fmaxf(acc[mi][ni][r] + bv, 0.f);
          if ((grow & 511) < 500) mx = fmaxf(mx, v);
        }
      mx = fmaxf(mx, __shfl_xor(mx, 16, 64));
      mx = fmaxf(mx, __shfl_xor(mx, 32, 64));
      if (quad == 0) red[wm * 128 + wn * 64 + ni * 16 + mrow] = mx;
    }
    __syncthreads();
    if (t < 128) {
      int col = n0 + t;
      if (col < N) {
        float m = fmaxf(red[t], red[128 + t]);
        int b = m0 >> 9;
        atomicMax((unsigned*)&outf[b * 512 + col], __float_as_uint(m));
      }
    }
  }
}

__global__ __launch_bounds__(256) void gemm_mfma(
    const u16* __restrict__ A, int lda, const float* __restrict__ X,
    const int* __restrict__ idx, int mode, const u16* __restrict__ Wb,
    int ldw, const float* __restrict__ bias, u16* __restrict__ C, int ldc,
    int Kp, int N, int act, float* __restrict__ outf) {
  __shared__ __align__(16) char smem[SMEM_BYTES];
  gemm_body(A, lda, X, idx, mode, Wb, ldw, bias, C, ldc, Kp, N, act, outf,
            blockIdx.x, blockIdx.y, smem, threadIdx.x);
}

// GEMM + FPS fused; FPS blocks FIRST (0..31), 4 batches/block (1 per wave)
__global__ __launch_bounds__(256) void gemm_fps(
    const u16* __restrict__ A, int lda, const float* __restrict__ X, int mode,
    const u16* __restrict__ Wb, int ldw, const float* __restrict__ bias,
    u16* __restrict__ C, int ldc, int Kp, int N, int act, int gx,
    const float* __restrict__ x, const int* __restrict__ init1,
    int* __restrict__ idx1, float* __restrict__ dstate,
    int* __restrict__ fstate, int t0, int tcnt) {
  __shared__ __align__(16) char smem[SMEM_BYTES];
  int bid = blockIdx.x;
  int t = threadIdx.x;
  if (bid < 32) {
    fps_block4((float4*)smem, x, init1, idx1, dstate, fstate, bid, t0, tcnt, t);
  } else {
    int g = bid - 32;
    int by = g / gx, bx = g - by * gx;
    gemm_body(A, lda, X, nullptr, mode, Wb, ldw, bias, C, ldc, Kp, N, act,
              nullptr, bx, by, smem, t);
  }
}

// ---------------------------------------------------------------------------
// prep (+ FPS seg0): 7 weight converts (K,N zero-padded) + zero(outf) +
// fused feat+l1 rows (layer-1 GEMM absorbed: 64 outs from 4 ins, scalar fp32)
// ---------------------------------------------------------------------------
struct PrepArgs {
  const float* wsrc[7];
  u16* wdst[7];
  int wN[7], wK[7], wKp[7];
  int wstart[8];
};

__global__ __launch_bounds__(256) void prep_kernel(
    PrepArgs pa, const float* __restrict__ x, const float* __restrict__ cW,
    const float* __restrict__ cb, const float* __restrict__ w1,
    const float* __restrict__ b1, u16* __restrict__ l1,
    float* __restrict__ outf, const int* __restrict__ init1,
    int* __restrict__ idx1, float* __restrict__ dstate,
    int* __restrict__ fstate, int tcnt) {
  __shared__ __align__(16) float4 cpt[2048];
  int bid = blockIdx.x;
  int t = threadIdx.x;
  if (bid < 32) {
    fps_block4(cpt, x, init1, idx1, dstate, fstate, bid, 0, tcnt, t);
    return;
  }
  int i = (bid - 32) * 256 + t;
  int S = pa.wstart[7];
  if (i < S) {
    int w = 0;
#pragma unroll
    for (int j = 1; j < 7; ++j)
      if (i >= pa.wstart[j]) w = j;
    int local = i - pa.wstart[w];
    int Kp = pa.wKp[w];
    int n = local / Kp, k = local - n * Kp;
    pa.wdst[w][local] =
        (n < pa.wN[w] && k < pa.wK[w]) ? f2bf(pa.wsrc[w][n * pa.wK[w] + k]) : (u16)0;
  } else if (i < S + 65536) {
    outf[i - S] = 0.f;
  } else {
    int r = i - S - 65536;
    if (r < M_AB) {
      float x0 = x[r * 3], x1 = x[r * 3 + 1], x2 = x[r * 3 + 2];
      float z = x0 * cW[0] + x1 * cW[1] + x2 * cW[2] + cb[0];
      float conf = 1.0f / (1.0f + expf(-z));
      u16* dst = l1 + (size_t)r * 64;
#pragma unroll
      for (int n8 = 0; n8 < 64; n8 += 8) {
        us8 v;
#pragma unroll
        for (int j = 0; j < 8; ++j) {
          const float* wr = w1 + (n8 + j) * 4;
          float a = fmaf(conf, wr[0], b1[n8 + j]);
          a = fmaf(x0, wr[1], a);
          a = fmaf(x1, wr[2], a);
          a = fmaf(x2, wr[3], a);
          v[j] = f2bf(fmaxf(a, 0.f));
        }
        *(us8*)(dst + n8) = v;
      }
    }
  }
}

// ---------------------------------------------------------------------------
extern "C" void kernel_launch(void* const* d_in, const int* in_sizes, int n_in,
                              void* d_out, int out_size, void* d_ws,
                              size_t ws_size, hipStream_t stream) {
  const float* x      = (const float*)d_in[0];
  const float* conf_W = (const float*)d_in[1];
  const float* conf_b = (const float*)d_in[2];
  const float* w1     = (const float*)d_in[3];
  const float* b1     = (const float*)d_in[4];
  const float* w2     = (const float*)d_in[5];
  const float* b2     = (const float*)d_in[6];
  const float* pc1_W  = (const float*)d_in[7];
  const float* pc1_b  = (const float*)d_in[8];
  const float* w3     = (const float*)d_in[9];
  const float* b3     = (const float*)d_in[10];
  const float* w4     = (const float*)d_in[11];
  const float* b4     = (const float*)d_in[12];
  const float* pc2_W  = (const float*)d_in[13];
  const float* pc2_b  = (const float*)d_in[14];
  const float* w5     = (const float*)d_in[15];
  const float* b5     = (const float*)d_in[16];
  const float* w6     = (const float*)d_in[17];
  const float* b6     = (const float*)d_in[18];
  const int* init1    = (const int*)d_in[20];

  char* ws = (char*)d_ws;
  u16* l2b  = (u16*)(ws + 0);
  u16* l4b  = (u16*)(ws + 0);
  u16* l6u  = (u16*)(ws + 0);
  u16* l1b  = (u16*)(ws + OFF_ARENA_B);
  u16* l3b  = (u16*)(ws + OFF_ARENA_B);
  u16* l5b  = (u16*)(ws + OFF_ARENA_B);
  u16* l7b  = (u16*)(ws + OFF_ARENA_B);
  int* idx1 = (int*)(ws + OFF_IDX1);
  float* dstate = (float*)(ws + OFF_FPSD);
  int* fstate   = (int*)(ws + OFF_FPSI);
  u16* wb   = (u16*)(ws + OFF_WB);
  float* outf = (float*)d_out;  // 128x512 fp32, accumulated via atomicMax

  // 7 weights (w1 handled in prep): w2, pc1, w3, w4, pc2, w5, w6
  PrepArgs pa;
  const float* srcs[7] = {w2, pc1_W, w3, w4, pc2_W, w5, w6};
  int Ns[7]  = {256, 256, 256, 384, 384, 384, 512};
  int Ks[7]  = {64, 256, 259, 256, 384, 387, 384};
  int Kps[7] = {64, 256, 320, 256, 384, 448, 384};
  u16* WBp[7];
  int cum = 0;
  for (int i = 0; i < 7; ++i) {
    pa.wsrc[i] = srcs[i];
    pa.wdst[i] = WBp[i] = wb + cum;
    pa.wN[i] = Ns[i];
    pa.wK[i] = Ks[i];
    pa.wKp[i] = Kps[i];
    pa.wstart[i] = cum;
    cum += Ns[i] * Kps[i];
  }
  pa.wstart[7] = cum;
  int total = cum + 65536 + M_AB;

  // FPS split over 6 dispatches: 40,50,70,100,110,130 (sum 500); done pre-C1
  prep_kernel<<<32 + (total + 255) / 256, 256, 0, stream>>>(
      pa, x, conf_W, conf_b, w1, b1, l1b, outf, init1, idx1, dstate, fstate, 40);
  // stage A (A1 absorbed into prep)
  gemm_fps<<<32 + 1000, 256, 0, stream>>>(l1b, 64, x, 0, WBp[0], 64,
      b2, l2b, 256, 64, 256, 1, 500, x, init1, idx1, dstate, fstate, 40, 50);
  gemm_fps<<<32 + 1000, 256, 0, stream>>>(l2b, 256, x, 0, WBp[1], 256,
      pc1_b, l3b, 256, 256, 256, 0, 500, x, init1, idx1, dstate, fstate, 90, 70);
  // stage B — unpermuted rows (no idx1 dependency)
  gemm_fps<<<32 + 1000, 256, 0, stream>>>(l3b, 256, x, 2, WBp[2], 320,
      b3, l4b, 256, 320, 256, 1, 500, x, init1, idx1, dstate, fstate, 160, 100);
  gemm_fps<<<32 + 1500, 256, 0, stream>>>(l4b, 256, x, 0, WBp[3], 256,
      b4, l5b, 384, 256, 384, 1, 500, x, init1, idx1, dstate, fstate, 260, 110);
  gemm_fps<<<32 + 1500, 256, 0, stream>>>(l5b, 384, x, 0, WBp[4], 384,
      pc2_b, l6u, 384, 384, 384, 0, 500, x, init1, idx1, dstate, fstate, 370, 130);
  // stage C — permutation applied here (mode 4), then final layer + max
  gemm_mfma<<<dim3(512, 3), 256, 0, stream>>>(l6u, 384, x, idx1, 4,
      WBp[5], 448, b5, l7b, 384, 448, 384, 1, nullptr);
  gemm_mfma<<<dim3(512, 4), 256, 0, stream>>>(l7b, 384, nullptr, nullptr, 0,
      WBp[6], 384, b6, nullptr, 0, 384, 512, 2, outf);
}

// Round 14
// 408.699 us; speedup vs baseline: 1.6039x; 1.0107x over previous
//
#include <hip/hip_runtime.h>

typedef unsigned short u16;
typedef short bf16x8 __attribute__((ext_vector_type(8)));   // 8 bf16 (4 VGPRs)
typedef float f32x4 __attribute__((ext_vector_type(4)));
typedef unsigned short us8 __attribute__((ext_vector_type(8)));
typedef unsigned long long u64;

__device__ __forceinline__ float bf2f(u16 u) {
  return __uint_as_float(((unsigned)u) << 16);
}
__device__ __forceinline__ u16 f2bf(float f) {
  unsigned u = __float_as_uint(f);
  u += 0x7fffu + ((u >> 16) & 1u);  // RNE (no NaNs in this workload)
  return (u16)(u >> 16);
}
__device__ __forceinline__ float rlf(float v, int l) {
  return __uint_as_float((unsigned)__builtin_amdgcn_readlane(__float_as_int(v), l));
}
// async global(16B/lane) -> LDS(wave-uniform base + lane*16) [m97-verified]
__device__ __forceinline__ void gload16(const u16* g, u16* l) {
  __builtin_amdgcn_global_load_lds(
      (const __attribute__((address_space(1))) void*)g,
      (__attribute__((address_space(3))) void*)l, 16, 0, 0);
}

// ---------------------------------------------------------------------------
// B=128, N=500. Stages A/B on 64000 unpermuted rows (permutation deferred to
// stage C). Stage C padded to 512 rows/batch -> 65536.
// ---------------------------------------------------------------------------
#define M_AB 64000
#define M_C 65536

#define OFF_ARENA_B 49152000u
#define OFF_IDX1 149815296u   // 128x500 int
#define OFF_FPSD 150071296u   // fps dist state
#define OFF_FPSI 150333440u   // fps fidx state
#define OFF_WB   150583296u   // bf16 weight arena (N,K padded)

// ---------------------------------------------------------------------------
// FPS: single chain per wave (80-VGPR profile), 4 waves/block = 4 batches.
// s_setprio 3: the FPS dependent chain is latency-critical (~300 issue
// slots/iter); co-resident GEMM waves are latency-tolerant. Priority gets
// the chain its slots promptly (in-situ per-iter 0.45 -> ~0.38 us).
// Exact fp32 (_rn, np sum order), np.argmax first-max tie-break.
// ---------------------------------------------------------------------------
template <int CTRL>
__device__ __forceinline__ float dppmaxf(float v) {
  int s = __builtin_amdgcn_update_dpp(0, __float_as_int(v), CTRL, 0xF, 0xF, true);
  return fmaxf(v, __uint_as_float((unsigned)s));
}

__device__ void fps_seg(const float4* cpt, int* out, const int* init1,
                        float* dstate, int* fstate, int b, int t0, int tcnt,
                        int lane) {
  __asm__ volatile("s_setprio 3");
  float px[8], py[8], pz[8], dist[8];
  int base = lane * 8;
#pragma unroll
  for (int j = 0; j < 8; ++j) {
    int p = base + j;
    float4 c = cpt[p < 500 ? p : 0];  // invalid slots duplicate point 0
    px[j] = c.x; py[j] = c.y; pz[j] = c.z;
  }
  int fidx;
  if (t0 == 0) {
#pragma unroll
    for (int j = 0; j < 8; ++j) dist[j] = 1e10f;
    fidx = init1[b];
  } else {
#pragma unroll
    for (int j = 0; j < 8; ++j) dist[j] = dstate[(b * 64 + lane) * 8 + j];
    fidx = fstate[b];
  }
  float4 c0 = cpt[fidx];
  float cx = c0.x, cy = c0.y, cz = c0.z;

  int tend = t0 + tcnt;
  for (int t = t0; t < tend; ++t) {
    if (lane == 0) out[t] = fidx;
    if (t == 499) { __asm__ volatile("s_setprio 0"); return; }
#pragma unroll
    for (int j = 0; j < 8; ++j) {
      float dx = __fsub_rn(px[j], cx);
      float dy = __fsub_rn(py[j], cy);
      float dz = __fsub_rn(pz[j], cz);
      float d = __fadd_rn(__fadd_rn(__fmul_rn(dx, dx), __fmul_rn(dy, dy)),
                          __fmul_rn(dz, dz));
      dist[j] = fminf(dist[j], d);
    }
    float m01 = fmaxf(dist[0], dist[1]), m23 = fmaxf(dist[2], dist[3]);
    float m45 = fmaxf(dist[4], dist[5]), m67 = fmaxf(dist[6], dist[7]);
    float lm = fmaxf(fmaxf(m01, m23), fmaxf(m45, m67));
    lm = dppmaxf<0x111>(lm);
    lm = dppmaxf<0x112>(lm);
    lm = dppmaxf<0x114>(lm);
    lm = dppmaxf<0x118>(lm);
    lm = dppmaxf<0x142>(lm);
    lm = dppmaxf<0x143>(lm);
    float mf = rlf(lm, 63);
    int sel = 8;
    float sx = 0.f, sy = 0.f, sz = 0.f;
#pragma unroll
    for (int j = 7; j >= 0; --j) {
      bool hit = (dist[j] == mf);
      sel = hit ? j : sel;
      sx = hit ? px[j] : sx;
      sy = hit ? py[j] : sy;
      sz = hit ? pz[j] : sz;
    }
    u64 mask = __ballot(sel != 8);
    int li = (int)__ffsll(mask) - 1;  // smallest lane = smallest point range
    fidx = li * 8 + __builtin_amdgcn_readlane(sel, li);
    cx = rlf(sx, li);
    cy = rlf(sy, li);
    cz = rlf(sz, li);
  }
#pragma unroll
  for (int j = 0; j < 8; ++j) dstate[(b * 64 + lane) * 8 + j] = dist[j];
  if (lane == 0) fstate[b] = fidx;
  __asm__ volatile("s_setprio 0");
}

// stage 4 batches' centroids into LDS, then each wave runs its own chain
__device__ __forceinline__ void fps_block4(float4* cpt, const float* x,
                                           const int* init1, int* idx1,
                                           float* dstate, int* fstate,
                                           int bid, int t0, int tcnt, int t) {
#pragma unroll
  for (int wv = 0; wv < 4; ++wv) {
    const float* xb = x + (size_t)(bid * 4 + wv) * 1500;
    for (int p = t; p < 500; p += 256)
      cpt[wv * 512 + p] =
          make_float4(xb[p * 3], xb[p * 3 + 1], xb[p * 3 + 2], 0.f);
  }
  __syncthreads();
  int wv = t >> 6;
  int b = bid * 4 + wv;
  fps_seg(cpt + wv * 512, idx1 + b * 500, init1, dstate, fstate, b, t0, tcnt,
          t & 63);
}

// ---------------------------------------------------------------------------
// MFMA GEMM body (round-10 proven structure): 128x128 tile, BK=64,
// global_load_lds staging, XOR-swizzled unpadded LDS [128][64]. 4 waves,
// each 64x64 (4x4 of 16x16x32).
// mode 0: plain rows; mode 2: direct concat (x[r] at lda..lda+2);
// mode 4: stage-C permuted gather (b=r>>9, p=r&511 clamp<500;
//         A row b*500+idx1[b*500+p], x at b*500+p).
// act: 0 none, 1 relu, 2 relu + per-batch col max -> atomicMax (512 r/b).
// ---------------------------------------------------------------------------
#define SMEM_BYTES (16384 * 2 + 1024)  // 33,792 B (also fits 4x512 float4 FPS)

__device__ __forceinline__ void gemm_body(
    const u16* __restrict__ A, int lda, const float* __restrict__ X,
    const int* __restrict__ idx, int mode, const u16* __restrict__ Wb,
    int ldw, const float* __restrict__ bias, u16* __restrict__ C, int ldc,
    int Kp, int N, int act, float* __restrict__ outf, int bx, int by,
    char* smem, int t) {
  u16* lA = (u16*)smem;
  u16* lB = (u16*)(smem + 16384);
  float* red = (float*)(smem + 32768);

  const int m0 = bx * 128, n0 = by * 128;
  const int w = t >> 6, lane = t & 63;
  const int mrow = lane & 15, quad = lane >> 4;
  const int wm = w >> 1, wn = w & 1;

  const int lrow8 = lane >> 3;
  const int sseg = (lane & 7) ^ lrow8;

  const u16* arow[4];
  const u16* wrow[4];
#pragma unroll
  for (int i = 0; i < 4; ++i) {
    int gr = m0 + w * 32 + i * 8 + lrow8;
    if (mode == 4) {
      int b = gr >> 9;
      int p = gr & 511;
      int pe = (p < 500) ? p : 0;
      int s = idx[b * 500 + pe];
      arow[i] = A + ((size_t)b * 500 + s) * lda;
    } else {
      arow[i] = A + (size_t)gr * lda;
    }
    wrow[i] = Wb + (size_t)(n0 + w * 32 + i * 8 + lrow8) * ldw;
  }
  // fallback (tail-chunk) coords: thread t covers row t>>1, segs (t&1)*4..+4
  const int fr = t >> 1;
  const int fs0 = (t & 1) * 4;
  const u16* faptr;
  const float* fxptr = nullptr;
  {
    int gr = m0 + fr;
    if (mode == 4) {
      int b = gr >> 9;
      int p = gr & 511;
      int pe = (p < 500) ? p : 0;
      int s = idx[b * 500 + pe];
      faptr = A + ((size_t)b * 500 + s) * lda;
      fxptr = X + ((size_t)b * 500 + pe) * 3;
    } else {
      faptr = A + (size_t)gr * lda;
      if (mode == 2) fxptr = X + (size_t)gr * 3;
    }
  }
  const int kfull = lda & ~63;

  f32x4 acc[4][4];
  const f32x4 fz = {0.f, 0.f, 0.f, 0.f};
#pragma unroll
  for (int i = 0; i < 4; ++i)
#pragma unroll
    for (int j = 0; j < 4; ++j) acc[i][j] = fz;

  for (int k0 = 0; k0 < Kp; k0 += 64) {
    __syncthreads();
#pragma unroll
    for (int i = 0; i < 4; ++i)
      gload16(wrow[i] + k0 + sseg * 8, lB + (w * 32 + i * 8) * 64);
    if (k0 < kfull) {
#pragma unroll
      for (int i = 0; i < 4; ++i)
        gload16(arow[i] + k0 + sseg * 8, lA + (w * 32 + i * 8) * 64);
    } else {
#pragma unroll
      for (int s4 = 0; s4 < 4; ++s4) {
        int seg = fs0 + s4;
        us8 v = {0, 0, 0, 0, 0, 0, 0, 0};
        int kb = k0 + seg * 8;
#pragma unroll
        for (int j = 0; j < 8; ++j) {
          int k = kb + j;
          u16 vv = 0;
          if (k < lda) vv = faptr[k];
          else if (mode != 0 && k < lda + 3) vv = f2bf(fxptr[k - lda]);
          v[j] = vv;
        }
        *(us8*)(lA + fr * 64 + (seg ^ (fr & 7)) * 8) = v;
      }
    }
    __syncthreads();

#pragma unroll
    for (int kh = 0; kh < 2; ++kh) {
      bf16x8 af[4], bfv[4];
#pragma unroll
      for (int mi = 0; mi < 4; ++mi) {
        int r = wm * 64 + mi * 16 + mrow;
        af[mi] = *(const bf16x8*)(lA + r * 64 + ((kh * 4 + quad) ^ (r & 7)) * 8);
      }
#pragma unroll
      for (int ni = 0; ni < 4; ++ni) {
        int r = wn * 64 + ni * 16 + mrow;
        bfv[ni] = *(const bf16x8*)(lB + r * 64 + ((kh * 4 + quad) ^ (r & 7)) * 8);
      }
#pragma unroll
      for (int mi = 0; mi < 4; ++mi)
#pragma unroll
        for (int ni = 0; ni < 4; ++ni)
          acc[mi][ni] = __builtin_amdgcn_mfma_f32_16x16x32_bf16(
              af[mi], bfv[ni], acc[mi][ni], 0, 0, 0);
    }
  }

  if (act < 2) {
#pragma unroll
    for (int ni = 0; ni < 4; ++ni) {
      int col = n0 + wn * 64 + ni * 16 + mrow;
      if (col >= N) continue;
      float bv = bias[col];
#pragma unroll
      for (int mi = 0; mi < 4; ++mi)
#pragma unroll
        for (int r = 0; r < 4; ++r) {
          int grow = m0 + wm * 64 + mi * 16 + quad * 4 + r;
          float v = acc[mi][ni][r] + bv;
          if (act == 1) v = fmaxf(v, 0.f);
          C[(size_t)grow * ldc + col] = f2bf(v);
        }
    }
  } else {
#pragma unroll
    for (int ni = 0; ni < 4; ++ni) {
      int col = n0 + wn * 64 + ni * 16 + mrow;
      float bv = (col < N) ? bias[col] : 0.f;
      float mx = 0.f;
#pragma unroll
      for (int mi = 0; mi < 4; ++mi)
#pragma unroll
        for (int r = 0; r < 4; ++r) {
          int grow = m0 + wm * 64 + mi * 16 + quad * 4 + r;
          float v = fmaxf(acc[mi][ni][r] + bv, 0.f);
          if ((grow & 511) < 500) mx = fmaxf(mx, v);
        }
      mx = fmaxf(mx, __shfl_xor(mx, 16, 64));
      mx = fmaxf(mx, __shfl_xor(mx, 32, 64));
      if (quad == 0) red[wm * 128 + wn * 64 + ni * 16 + mrow] = mx;
    }
    __syncthreads();
    if (t < 128) {
      int col = n0 + t;
      if (col < N) {
        float m = fmaxf(red[t], red[128 + t]);
        int b = m0 >> 9;
        atomicMax((unsigned*)&outf[b * 512 + col], __float_as_uint(m));
      }
    }
  }
}

__global__ __launch_bounds__(256) void gemm_mfma(
    const u16* __restrict__ A, int lda, const float* __restrict__ X,
    const int* __restrict__ idx, int mode, const u16* __restrict__ Wb,
    int ldw, const float* __restrict__ bias, u16* __restrict__ C, int ldc,
    int Kp, int N, int act, float* __restrict__ outf) {
  __shared__ __align__(16) char smem[SMEM_BYTES];
  gemm_body(A, lda, X, idx, mode, Wb, ldw, bias, C, ldc, Kp, N, act, outf,
            blockIdx.x, blockIdx.y, smem, threadIdx.x);
}

// GEMM + FPS fused; FPS blocks FIRST (0..31), 4 batches/block (1 per wave)
__global__ __launch_bounds__(256) void gemm_fps(
    const u16* __restrict__ A, int lda, const float* __restrict__ X, int mode,
    const u16* __restrict__ Wb, int ldw, const float* __restrict__ bias,
    u16* __restrict__ C, int ldc, int Kp, int N, int act, int gx,
    const float* __restrict__ x, const int* __restrict__ init1,
    int* __restrict__ idx1, float* __restrict__ dstate,
    int* __restrict__ fstate, int t0, int tcnt) {
  __shared__ __align__(16) char smem[SMEM_BYTES];
  int bid = blockIdx.x;
  int t = threadIdx.x;
  if (bid < 32) {
    fps_block4((float4*)smem, x, init1, idx1, dstate, fstate, bid, t0, tcnt, t);
  } else {
    int g = bid - 32;
    int by = g / gx, bx = g - by * gx;
    gemm_body(A, lda, X, nullptr, mode, Wb, ldw, bias, C, ldc, Kp, N, act,
              nullptr, bx, by, smem, t);
  }
}

// ---------------------------------------------------------------------------
// prep (+ FPS seg0): 7 weight converts (K,N zero-padded) + zero(outf) +
// fused feat+l1 rows (layer-1 GEMM absorbed: 64 outs from 4 ins, scalar fp32)
// ---------------------------------------------------------------------------
struct PrepArgs {
  const float* wsrc[7];
  u16* wdst[7];
  int wN[7], wK[7], wKp[7];
  int wstart[8];
};

__global__ __launch_bounds__(256) void prep_kernel(
    PrepArgs pa, const float* __restrict__ x, const float* __restrict__ cW,
    const float* __restrict__ cb, const float* __restrict__ w1,
    const float* __restrict__ b1, u16* __restrict__ l1,
    float* __restrict__ outf, const int* __restrict__ init1,
    int* __restrict__ idx1, float* __restrict__ dstate,
    int* __restrict__ fstate, int tcnt) {
  __shared__ __align__(16) float4 cpt[2048];
  int bid = blockIdx.x;
  int t = threadIdx.x;
  if (bid < 32) {
    fps_block4(cpt, x, init1, idx1, dstate, fstate, bid, 0, tcnt, t);
    return;
  }
  int i = (bid - 32) * 256 + t;
  int S = pa.wstart[7];
  if (i < S) {
    int w = 0;
#pragma unroll
    for (int j = 1; j < 7; ++j)
      if (i >= pa.wstart[j]) w = j;
    int local = i - pa.wstart[w];
    int Kp = pa.wKp[w];
    int n = local / Kp, k = local - n * Kp;
    pa.wdst[w][local] =
        (n < pa.wN[w] && k < pa.wK[w]) ? f2bf(pa.wsrc[w][n * pa.wK[w] + k]) : (u16)0;
  } else if (i < S + 65536) {
    outf[i - S] = 0.f;
  } else {
    int r = i - S - 65536;
    if (r < M_AB) {
      float x0 = x[r * 3], x1 = x[r * 3 + 1], x2 = x[r * 3 + 2];
      float z = x0 * cW[0] + x1 * cW[1] + x2 * cW[2] + cb[0];
      float conf = 1.0f / (1.0f + expf(-z));
      u16* dst = l1 + (size_t)r * 64;
#pragma unroll
      for (int n8 = 0; n8 < 64; n8 += 8) {
        us8 v;
#pragma unroll
        for (int j = 0; j < 8; ++j) {
          const float* wr = w1 + (n8 + j) * 4;
          float a = fmaf(conf, wr[0], b1[n8 + j]);
          a = fmaf(x0, wr[1], a);
          a = fmaf(x1, wr[2], a);
          a = fmaf(x2, wr[3], a);
          v[j] = f2bf(fmaxf(a, 0.f));
        }
        *(us8*)(dst + n8) = v;
      }
    }
  }
}

// ---------------------------------------------------------------------------
extern "C" void kernel_launch(void* const* d_in, const int* in_sizes, int n_in,
                              void* d_out, int out_size, void* d_ws,
                              size_t ws_size, hipStream_t stream) {
  const float* x      = (const float*)d_in[0];
  const float* conf_W = (const float*)d_in[1];
  const float* conf_b = (const float*)d_in[2];
  const float* w1     = (const float*)d_in[3];
  const float* b1     = (const float*)d_in[4];
  const float* w2     = (const float*)d_in[5];
  const float* b2     = (const float*)d_in[6];
  const float* pc1_W  = (const float*)d_in[7];
  const float* pc1_b  = (const float*)d_in[8];
  const float* w3     = (const float*)d_in[9];
  const float* b3     = (const float*)d_in[10];
  const float* w4     = (const float*)d_in[11];
  const float* b4     = (const float*)d_in[12];
  const float* pc2_W  = (const float*)d_in[13];
  const float* pc2_b  = (const float*)d_in[14];
  const float* w5     = (const float*)d_in[15];
  const float* b5     = (const float*)d_in[16];
  const float* w6     = (const float*)d_in[17];
  const float* b6     = (const float*)d_in[18];
  const int* init1    = (const int*)d_in[20];

  char* ws = (char*)d_ws;
  u16* l2b  = (u16*)(ws + 0);
  u16* l4b  = (u16*)(ws + 0);
  u16* l6u  = (u16*)(ws + 0);
  u16* l1b  = (u16*)(ws + OFF_ARENA_B);
  u16* l3b  = (u16*)(ws + OFF_ARENA_B);
  u16* l5b  = (u16*)(ws + OFF_ARENA_B);
  u16* l7b  = (u16*)(ws + OFF_ARENA_B);
  int* idx1 = (int*)(ws + OFF_IDX1);
  float* dstate = (float*)(ws + OFF_FPSD);
  int* fstate   = (int*)(ws + OFF_FPSI);
  u16* wb   = (u16*)(ws + OFF_WB);
  float* outf = (float*)d_out;  // 128x512 fp32, accumulated via atomicMax

  // 7 weights (w1 handled in prep): w2, pc1, w3, w4, pc2, w5, w6
  PrepArgs pa;
  const float* srcs[7] = {w2, pc1_W, w3, w4, pc2_W, w5, w6};
  int Ns[7]  = {256, 256, 256, 384, 384, 384, 512};
  int Ks[7]  = {64, 256, 259, 256, 384, 387, 384};
  int Kps[7] = {64, 256, 320, 256, 384, 448, 384};
  u16* WBp[7];
  int cum = 0;
  for (int i = 0; i < 7; ++i) {
    pa.wsrc[i] = srcs[i];
    pa.wdst[i] = WBp[i] = wb + cum;
    pa.wN[i] = Ns[i];
    pa.wK[i] = Ks[i];
    pa.wKp[i] = Kps[i];
    pa.wstart[i] = cum;
    cum += Ns[i] * Kps[i];
  }
  pa.wstart[7] = cum;
  int total = cum + 65536 + M_AB;

  // FPS split over 6 dispatches: 65,75,90,90,90,90 (sum 500), sized to the
  // GEMM-only floor of each host dispatch; done before C1.
  prep_kernel<<<32 + (total + 255) / 256, 256, 0, stream>>>(
      pa, x, conf_W, conf_b, w1, b1, l1b, outf, init1, idx1, dstate, fstate, 65);
  // stage A (A1 absorbed into prep)
  gemm_fps<<<32 + 1000, 256, 0, stream>>>(l1b, 64, x, 0, WBp[0], 64,
      b2, l2b, 256, 64, 256, 1, 500, x, init1, idx1, dstate, fstate, 65, 75);
  gemm_fps<<<32 + 1000, 256, 0, stream>>>(l2b, 256, x, 0, WBp[1], 256,
      pc1_b, l3b, 256, 256, 256, 0, 500, x, init1, idx1, dstate, fstate, 140, 90);
  // stage B — unpermuted rows (no idx1 dependency)
  gemm_fps<<<32 + 1000, 256, 0, stream>>>(l3b, 256, x, 2, WBp[2], 320,
      b3, l4b, 256, 320, 256, 1, 500, x, init1, idx1, dstate, fstate, 230, 90);
  gemm_fps<<<32 + 1500, 256, 0, stream>>>(l4b, 256, x, 0, WBp[3], 256,
      b4, l5b, 384, 256, 384, 1, 500, x, init1, idx1, dstate, fstate, 320, 90);
  gemm_fps<<<32 + 1500, 256, 0, stream>>>(l5b, 384, x, 0, WBp[4], 384,
      pc2_b, l6u, 384, 384, 384, 0, 500, x, init1, idx1, dstate, fstate, 410, 90);
  // stage C — permutation applied here (mode 4), then final layer + max
  gemm_mfma<<<dim3(512, 3), 256, 0, stream>>>(l6u, 384, x, idx1, 4,
      WBp[5], 448, b5, l7b, 384, 448, 384, 1, nullptr);
  gemm_mfma<<<dim3(512, 4), 256, 0, stream>>>(l7b, 384, nullptr, nullptr, 0,
      WBp[6], 384, b6, nullptr, 0, 384, 512, 2, outf);
}